// Round 5
// baseline (436.912 us; speedup 1.0000x reference)
//
#include <hip/hip_runtime.h>

#define NWIN 4096
#define EPSF 1e-6f
#define GRID_MAIN 512
#define BLOCK_MAIN 512

// fixed-point scales (u32 LDS atomics; native ds_add_u32, fire-and-forget)
#define SCALE_P   2097152.0f     // 2^21  sum_p   (<=1150*2^21 = 2.4e9 < 4.29e9)
#define SCALE_R   131072.0f      // 2^17  agg_rate / sum_pd (<=1150*5.5*2^17 = 8.3e8)
#define INV_P     (1.0/2097152.0)
#define INV_R     (1.0/131072.0)
#define SCALE_CE  1048576.0f     // 2^20  CE num/den (scales cancel in the ratio)

// ---------------- workspace layout (bytes) ----------------
//  byte 0:  u64 ce_num        byte 8:  u64 ce_den
//  byte 16: u32 n_valid(u[4]) byte 20: u32 n_mask(u[5])
//  byte 24: f32 ref_dobs(f[6]) byte 28: f32 frac(f[7])
//  byte 32,36: u32 prefixes (u[8],u[9])  byte 40,44: u32 ranks (u[10],u[11])
#define OFF_SEG   256            // float g_seg[16384]
#define OFF_H1    65792          // u32[2048]
#define OFF_H2    73984          // u32[2*2048]
#define OFF_H3    90368          // u32[2*1024]
#define OFF_SEGU  131072         // u32 g_seg_u32[16384] (no-part fallback)
#define OFF_PART  262144         // GRID_MAIN x 64KB u32 partials; keys after

__device__ __forceinline__ unsigned make_key_raw(const float4* __restrict__ xraw,
                                                 const int* __restrict__ mask,
                                                 const int* __restrict__ widx, int i)
{
    int wi = widx[i];
    int m = mask[i];
    if (wi < 0 || !m) return 0x7F800000u;
    float d = fmaxf(xraw[i].z, 0.0f);
    unsigned k = __float_as_uint(d);
    return (k == 0x80000000u) ? 0u : k;
}

// ---------------- per-element fused work (u32 fixed-point atomics) ----------------
__device__ __forceinline__ void process_elem(
    float lgx, float lgy, int yi, int mi, float xz, float xw, int wi,
    float cw0, float cw1, unsigned* keyOut,
    float& num, float& den, unsigned& nv, unsigned& nm, unsigned& zc,
    unsigned* s_seg, unsigned* s_h1)
{
    float wy = yi ? cw1 : cw0;
    float mx = fmaxf(lgx, lgy);
    float lse = mx + __logf(__expf(lgx - mx) + __expf(lgy - mx));
    float nll = lse - (yi ? lgy : lgx);
    if (mi) { nm++; num += wy * nll; den += wy; }

    bool vq = (wi >= 0) && mi;
    unsigned key = 0x7F800000u;
    if (vq) {
        nv++;
        float d = fmaxf(xz, 0.0f);
        key = __float_as_uint(d);
        if (key == 0x80000000u) key = 0u;
    }
    *keyOut = key;

    if (key == 0u) zc++;
    else atomicAdd(&s_h1[key >> 21], 1u);

    if (vq && wi < NWIN) {
        float p = 1.0f / (1.0f + __expf(lgx - lgy));
        float rate = fmaxf(xw, 0.0f);
        float dob  = fmaxf(xz, 0.0f);
        atomicAdd(&s_seg[wi], 1u);
        atomicAdd(&s_seg[NWIN + wi],     (unsigned)(p * SCALE_P + 0.5f));
        atomicAdd(&s_seg[2 * NWIN + wi], (unsigned)(p * rate * SCALE_R + 0.5f));
        atomicAdd(&s_seg[3 * NWIN + wi], (unsigned)(p * dob  * SCALE_R + 0.5f));
    }
}

// minimal variant for the atomic-ablation kernel (no CE math)
__device__ __forceinline__ void ablate_elem(
    float lgx, float lgy, int mi, float xz, float xw, int wi,
    unsigned& zc, unsigned* s_seg, unsigned* s_h1)
{
    bool vq = (wi >= 0) && mi;
    unsigned key = 0x7F800000u;
    if (vq) {
        float d = fmaxf(xz, 0.0f);
        key = __float_as_uint(d);
        if (key == 0x80000000u) key = 0u;
    }
    if (key == 0u) zc++;
    else atomicAdd(&s_h1[key >> 21], 1u);
    if (vq && wi < NWIN) {
        float p = 1.0f / (1.0f + __expf(lgx - lgy));
        float rate = fmaxf(xw, 0.0f);
        float dob  = fmaxf(xz, 0.0f);
        atomicAdd(&s_seg[wi], 1u);
        atomicAdd(&s_seg[NWIN + wi],     (unsigned)(p * SCALE_P + 0.5f));
        atomicAdd(&s_seg[2 * NWIN + wi], (unsigned)(p * rate * SCALE_R + 0.5f));
        atomicAdd(&s_seg[3 * NWIN + wi], (unsigned)(p * dob  * SCALE_R + 0.5f));
    }
}

// ---------------- ABLATION A: pure 9-stream load ----------------
extern "C" __global__ __launch_bounds__(BLOCK_MAIN)
void k_abl_load(const float2* __restrict__ logits, const int* __restrict__ y,
                const int* __restrict__ mask, const float4* __restrict__ xraw,
                const int* __restrict__ widx, unsigned* __restrict__ scratch, int n)
{
    const int nth = GRID_MAIN * BLOCK_MAIN;
    const int gtid = blockIdx.x * BLOCK_MAIN + threadIdx.x;
    const int nq = n >> 2;
    const float4* lg4 = (const float4*)logits;
    const int4* y4p = (const int4*)y;
    const int4* m4p = (const int4*)mask;
    const int4* w4p = (const int4*)widx;
    float fs = 0.0f; int is = 0;
    for (int q = gtid; q < nq; q += nth) {
        float4 lgA = lg4[2 * q], lgB = lg4[2 * q + 1];
        int4 y4 = y4p[q], m4 = m4p[q], w4 = w4p[q];
        float4 x0 = xraw[4 * q], x1 = xraw[4 * q + 1];
        float4 x2 = xraw[4 * q + 2], x3 = xraw[4 * q + 3];
        fs += lgA.x + lgA.y + lgA.z + lgA.w + lgB.x + lgB.y + lgB.z + lgB.w
            + x0.z + x0.w + x1.z + x1.w + x2.z + x2.w + x3.z + x3.w;
        is += y4.x + y4.y + y4.z + y4.w + m4.x + m4.y + m4.z + m4.w
            + w4.x + w4.y + w4.z + w4.w;
    }
    scratch[gtid] = (unsigned)is + __float_as_uint(fs);   // keep-alive
}

// ---------------- ABLATION B: loads + u32 LDS atomics ----------------
extern "C" __global__ __launch_bounds__(BLOCK_MAIN)
void k_abl_atom(const float2* __restrict__ logits, const int* __restrict__ y,
                const int* __restrict__ mask, const float4* __restrict__ xraw,
                const int* __restrict__ widx, unsigned* __restrict__ scratch, int n)
{
    __shared__ unsigned s_seg[4 * NWIN];
    __shared__ unsigned s_h1[2048];
    for (int j = threadIdx.x; j < 4 * NWIN; j += BLOCK_MAIN) s_seg[j] = 0u;
    for (int j = threadIdx.x; j < 2048; j += BLOCK_MAIN) s_h1[j] = 0u;
    __syncthreads();
    const int nth = GRID_MAIN * BLOCK_MAIN;
    const int gtid = blockIdx.x * BLOCK_MAIN + threadIdx.x;
    const int nq = n >> 2;
    const float4* lg4 = (const float4*)logits;
    const int4* y4p = (const int4*)y;
    const int4* m4p = (const int4*)mask;
    const int4* w4p = (const int4*)widx;
    unsigned zc = 0u; float fs = 0.0f; int is = 0;
    for (int q = gtid; q < nq; q += nth) {
        float4 lgA = lg4[2 * q], lgB = lg4[2 * q + 1];
        int4 y4 = y4p[q], m4 = m4p[q], w4 = w4p[q];
        float4 x0 = xraw[4 * q], x1 = xraw[4 * q + 1];
        float4 x2 = xraw[4 * q + 2], x3 = xraw[4 * q + 3];
        fs += lgA.z + lgB.z; is += y4.x + y4.z;   // consume streams not used below
        ablate_elem(lgA.x, lgA.y, m4.x, x0.z, x0.w, w4.x, zc, s_seg, s_h1);
        ablate_elem(lgA.z, lgA.w, m4.y, x1.z, x1.w, w4.y, zc, s_seg, s_h1);
        ablate_elem(lgB.x, lgB.y, m4.z, x2.z, x2.w, w4.z, zc, s_seg, s_h1);
        ablate_elem(lgB.z, lgB.w, m4.w, x3.z, x3.w, w4.w, zc, s_seg, s_h1);
    }
    __syncthreads();
    // flush into this block's private scratch slice (k_main overwrites later)
    unsigned* dst = scratch + (size_t)blockIdx.x * (4 * NWIN);
    for (int j = threadIdx.x; j < 4 * NWIN; j += BLOCK_MAIN)
        dst[j] = s_seg[j] + ((j < 2048) ? s_h1[j] : zc);
}

// ---------------- main fused pass ----------------
extern "C" __global__ __launch_bounds__(BLOCK_MAIN)
void k_main(const float2* __restrict__ logits, const int* __restrict__ y,
            const int* __restrict__ mask, const float4* __restrict__ xraw,
            const int* __restrict__ widx, const float* __restrict__ cw,
            unsigned long long* __restrict__ ws_u64, unsigned* __restrict__ ws_u,
            unsigned* __restrict__ g_seg_u32, unsigned* __restrict__ part,
            unsigned* __restrict__ keys, unsigned* __restrict__ gh1,
            int use_part, int use_keys, int n)
{
    __shared__ unsigned s_seg[4 * NWIN];   // 64 KB: cnt | sum_p<<21 | rate<<17 | pd<<17
    __shared__ unsigned s_h1[2048];        // 8 KB level-1 histogram
    for (int j = threadIdx.x; j < 4 * NWIN; j += BLOCK_MAIN) s_seg[j] = 0u;
    for (int j = threadIdx.x; j < 2048; j += BLOCK_MAIN) s_h1[j] = 0u;
    __syncthreads();

    const float cw0 = cw[0], cw1 = cw[1];
    float num = 0.0f, den = 0.0f;
    unsigned nv = 0u, nm = 0u, zc = 0u;

    const int nth = GRID_MAIN * BLOCK_MAIN;
    const int gtid = blockIdx.x * BLOCK_MAIN + threadIdx.x;
    const int nq = n >> 2;

    const float4* lg4 = (const float4*)logits;
    const int4* y4p = (const int4*)y;
    const int4* m4p = (const int4*)mask;
    const int4* w4p = (const int4*)widx;

    for (int q = gtid; q < nq; q += nth) {
        float4 lgA = lg4[2 * q], lgB = lg4[2 * q + 1];
        int4 y4 = y4p[q], m4 = m4p[q], w4 = w4p[q];
        float4 x0 = xraw[4 * q], x1 = xraw[4 * q + 1];
        float4 x2 = xraw[4 * q + 2], x3 = xraw[4 * q + 3];

        uint4 kq;
        process_elem(lgA.x, lgA.y, y4.x, m4.x, x0.z, x0.w, w4.x,
                     cw0, cw1, &kq.x, num, den, nv, nm, zc, s_seg, s_h1);
        process_elem(lgA.z, lgA.w, y4.y, m4.y, x1.z, x1.w, w4.y,
                     cw0, cw1, &kq.y, num, den, nv, nm, zc, s_seg, s_h1);
        process_elem(lgB.x, lgB.y, y4.z, m4.z, x2.z, x2.w, w4.z,
                     cw0, cw1, &kq.z, num, den, nv, nm, zc, s_seg, s_h1);
        process_elem(lgB.z, lgB.w, y4.w, m4.w, x3.z, x3.w, w4.w,
                     cw0, cw1, &kq.w, num, den, nv, nm, zc, s_seg, s_h1);
        if (use_keys) ((uint4*)keys)[q] = kq;
    }
    for (int i = (nq << 2) + gtid; i < n; i += nth) {   // tail (n%4)
        float2 lg = logits[i];
        float4 xr = xraw[i];
        unsigned k;
        process_elem(lg.x, lg.y, y[i], mask[i], xr.z, xr.w, widx[i],
                     cw0, cw1, &k, num, den, nv, nm, zc, s_seg, s_h1);
        if (use_keys) keys[i] = k;
    }

    for (int off = 32; off > 0; off >>= 1) {
        num += __shfl_down(num, off);
        den += __shfl_down(den, off);
        nv  += __shfl_down(nv, off);
        nm  += __shfl_down(nm, off);
        zc  += __shfl_down(zc, off);
    }
    if ((threadIdx.x & 63) == 0) {
        atomicAdd(&ws_u64[0], (unsigned long long)(num * SCALE_CE + 0.5f));
        atomicAdd(&ws_u64[1], (unsigned long long)(den * SCALE_CE + 0.5f));
        atomicAdd(&ws_u[4], nv);
        atomicAdd(&ws_u[5], nm);
        if (zc) atomicAdd(&s_h1[0], zc);
    }
    __syncthreads();

    if (use_part) {
        uint4* dst = (uint4*)(part + (size_t)blockIdx.x * (4 * NWIN));
        const uint4* src = (const uint4*)s_seg;
        for (int j = threadIdx.x; j < NWIN; j += BLOCK_MAIN) dst[j] = src[j];
    } else {
        for (int j = threadIdx.x; j < 4 * NWIN; j += BLOCK_MAIN) {
            unsigned v = s_seg[j];
            if (v) atomicAdd(&g_seg_u32[j], v);
        }
    }
    for (int j = threadIdx.x; j < 2048; j += BLOCK_MAIN) {
        unsigned v = s_h1[j];
        if (v) atomicAdd(&gh1[j], v);
    }
}

// ---------------- partial reduction: 512 u32 partials -> float g_seg ----------------
extern "C" __global__ __launch_bounds__(128)
void k_reduce(const unsigned* __restrict__ part, float* __restrict__ g_seg)
{
    const int j = blockIdx.x * 128 + threadIdx.x;   // grid 128 -> 16384 bins
    const unsigned* p = part + j;
    unsigned long long s = 0ull;
#pragma unroll 8
    for (int b = 0; b < GRID_MAIN; ++b) s += p[(size_t)b * (4 * NWIN)];
    double inv = (j < NWIN) ? 1.0 : (j < 2 * NWIN) ? INV_P : INV_R;
    g_seg[j] = (float)((double)s * inv);
}

// fallback when no part buffer: convert global u32 sums to float
extern "C" __global__ __launch_bounds__(256)
void k_convert(const unsigned* __restrict__ gsu, float* __restrict__ g_seg)
{
    const int j = blockIdx.x * 256 + threadIdx.x;   // grid 64
    double inv = (j < NWIN) ? 1.0 : (j < 2 * NWIN) ? INV_P : INV_R;
    g_seg[j] = (float)((double)gsu[j] * inv);
}

// ---------------- histogram passes 2 and 3 ----------------
extern "C" __global__ __launch_bounds__(256)
void k_hist2(const unsigned* __restrict__ keys, const float4* __restrict__ xraw,
             const int* __restrict__ mask, const int* __restrict__ widx,
             int use_keys, int n, const unsigned* __restrict__ ws_u,
             unsigned* __restrict__ gh)
{
    __shared__ unsigned h[2 * 2048];
    for (int j = threadIdx.x; j < 2 * 2048; j += 256) h[j] = 0u;
    __syncthreads();
    const unsigned p0 = ws_u[8], p1 = ws_u[9];
    const int nth = gridDim.x * blockDim.x;
    const int gtid = blockIdx.x * blockDim.x + threadIdx.x;
    if (use_keys) {
        const uint4* k4 = (const uint4*)keys;
        const int nq = n >> 2;
        for (int q = gtid; q < nq; q += nth) {
            uint4 kk = k4[q];
#pragma unroll
            for (int e = 0; e < 4; ++e) {
                unsigned key = (e == 0) ? kk.x : (e == 1) ? kk.y : (e == 2) ? kk.z : kk.w;
                unsigned top = key >> 21;
                unsigned sub = (key >> 10) & 2047u;
                if (top == p0) atomicAdd(&h[sub], 1u);
                if (top == p1) atomicAdd(&h[2048 + sub], 1u);
            }
        }
        for (int i = (nq << 2) + gtid; i < n; i += nth) {
            unsigned key = keys[i];
            unsigned top = key >> 21, sub = (key >> 10) & 2047u;
            if (top == p0) atomicAdd(&h[sub], 1u);
            if (top == p1) atomicAdd(&h[2048 + sub], 1u);
        }
    } else {
        for (int i = gtid; i < n; i += nth) {
            unsigned key = make_key_raw(xraw, mask, widx, i);
            unsigned top = key >> 21, sub = (key >> 10) & 2047u;
            if (top == p0) atomicAdd(&h[sub], 1u);
            if (top == p1) atomicAdd(&h[2048 + sub], 1u);
        }
    }
    __syncthreads();
    for (int j = threadIdx.x; j < 2 * 2048; j += 256)
        if (h[j]) atomicAdd(&gh[j], h[j]);
}

extern "C" __global__ __launch_bounds__(256)
void k_hist3(const unsigned* __restrict__ keys, const float4* __restrict__ xraw,
             const int* __restrict__ mask, const int* __restrict__ widx,
             int use_keys, int n, const unsigned* __restrict__ ws_u,
             unsigned* __restrict__ gh)
{
    __shared__ unsigned h[2 * 1024];
    for (int j = threadIdx.x; j < 2 * 1024; j += 256) h[j] = 0u;
    __syncthreads();
    const unsigned p0 = ws_u[8], p1 = ws_u[9];
    const int nth = gridDim.x * blockDim.x;
    const int gtid = blockIdx.x * blockDim.x + threadIdx.x;
    if (use_keys) {
        const uint4* k4 = (const uint4*)keys;
        const int nq = n >> 2;
        for (int q = gtid; q < nq; q += nth) {
            uint4 kk = k4[q];
#pragma unroll
            for (int e = 0; e < 4; ++e) {
                unsigned key = (e == 0) ? kk.x : (e == 1) ? kk.y : (e == 2) ? kk.z : kk.w;
                unsigned top = key >> 10, sub = key & 1023u;
                if (top == p0) atomicAdd(&h[sub], 1u);
                if (top == p1) atomicAdd(&h[1024 + sub], 1u);
            }
        }
        for (int i = (nq << 2) + gtid; i < n; i += nth) {
            unsigned key = keys[i];
            unsigned top = key >> 10, sub = key & 1023u;
            if (top == p0) atomicAdd(&h[sub], 1u);
            if (top == p1) atomicAdd(&h[1024 + sub], 1u);
        }
    } else {
        for (int i = gtid; i < n; i += nth) {
            unsigned key = make_key_raw(xraw, mask, widx, i);
            unsigned top = key >> 10, sub = key & 1023u;
            if (top == p0) atomicAdd(&h[sub], 1u);
            if (top == p1) atomicAdd(&h[1024 + sub], 1u);
        }
    }
    __syncthreads();
    for (int j = threadIdx.x; j < 2 * 1024; j += 256)
        if (h[j]) atomicAdd(&gh[j], h[j]);
}

// ---------------- single-block scan + rank search ----------------
__device__ void scan_search(const unsigned* __restrict__ gh, int NB, unsigned rank,
                            unsigned* sv, unsigned* wsb, unsigned* ret)
{
    const int tid = threadIdx.x;
    for (int j = tid; j < NB; j += 256) sv[j] = gh[j];
    __syncthreads();
    const int E = NB >> 8;
    const int base = tid * E;
    unsigned loc = 0u;
    for (int e = 0; e < E; ++e) loc += sv[base + e];
    unsigned inc = loc;
    const int lane = tid & 63;
    for (int off = 1; off < 64; off <<= 1) {
        unsigned u = __shfl_up(inc, off);
        if (lane >= off) inc += u;
    }
    const int wid = tid >> 6;
    if (lane == 63) wsb[wid] = inc;
    __syncthreads();
    if (tid == 0) {
        unsigned run = 0u;
        for (int w = 0; w < 4; ++w) { unsigned t = wsb[w]; wsb[w] = run; run += t; }
    }
    __syncthreads();
    unsigned c = wsb[wid] + (inc - loc);
    for (int e = 0; e < E; ++e) {
        unsigned hv = sv[base + e];
        if (rank >= c && rank < c + hv) { ret[0] = (unsigned)(base + e); ret[1] = rank - c; }
        c += hv;
    }
    __syncthreads();
}

extern "C" __global__ __launch_bounds__(256)
void k_scan1(unsigned* __restrict__ ws_u, float* __restrict__ ws_f,
             const unsigned* __restrict__ gh)
{
    __shared__ unsigned sv[2048];
    __shared__ unsigned wsb[4];
    __shared__ unsigned ret[2];
    __shared__ unsigned rk[2];
    if (threadIdx.x == 0) {
        int n = (int)ws_u[4];
        float nf = (float)(n - 1);
        float pos = fmaxf(0.75f * nf, 0.0f);
        float lo = floorf(pos);
        ws_f[7] = pos - lo;
        rk[0] = (unsigned)lo;
        rk[1] = (unsigned)ceilf(pos);
    }
    __syncthreads();
    unsigned r0 = rk[0], r1 = rk[1];
    scan_search(gh, 2048, r0, sv, wsb, ret);
    if (threadIdx.x == 0) { ws_u[8] = ret[0]; ws_u[10] = ret[1]; }
    scan_search(gh, 2048, r1, sv, wsb, ret);
    if (threadIdx.x == 0) { ws_u[9] = ret[0]; ws_u[11] = ret[1]; }
}

extern "C" __global__ __launch_bounds__(256)
void k_scan2(unsigned* __restrict__ ws_u, const unsigned* __restrict__ gh)
{
    __shared__ unsigned sv[2048];
    __shared__ unsigned wsb[4];
    __shared__ unsigned ret[2];
    unsigned p0 = ws_u[8], p1 = ws_u[9];
    unsigned r0 = ws_u[10], r1 = ws_u[11];
    scan_search(gh, 2048, r0, sv, wsb, ret);
    if (threadIdx.x == 0) { ws_u[8] = (p0 << 11) | ret[0]; ws_u[10] = ret[1]; }
    scan_search(gh + 2048, 2048, r1, sv, wsb, ret);
    if (threadIdx.x == 0) { ws_u[9] = (p1 << 11) | ret[0]; ws_u[11] = ret[1]; }
}

extern "C" __global__ __launch_bounds__(256)
void k_scan3(unsigned* __restrict__ ws_u, float* __restrict__ ws_f,
             const unsigned* __restrict__ gh)
{
    __shared__ unsigned sv[2048];
    __shared__ unsigned wsb[4];
    __shared__ unsigned ret[2];
    unsigned p0 = ws_u[8], p1 = ws_u[9];
    unsigned r0 = ws_u[10], r1 = ws_u[11];
    scan_search(gh, 1024, r0, sv, wsb, ret);
    float v0 = __uint_as_float((p0 << 10) | ret[0]);
    scan_search(gh + 1024, 1024, r1, sv, wsb, ret);
    float v1 = __uint_as_float((p1 << 10) | ret[0]);
    if (threadIdx.x == 0) {
        int n = (int)ws_u[4];
        float frac = ws_f[7];
        float q = v0 * (1.0f - frac) + v1 * frac;
        ws_f[6] = (n > 0) ? fmaxf(q, EPSF) : 1.0f;
    }
}

// ---------------- finalize ----------------
extern "C" __global__ __launch_bounds__(1024)
void k_final(const float* __restrict__ g_seg, const unsigned long long* __restrict__ ws_u64,
             const float* __restrict__ ws_f, const unsigned* __restrict__ ws_u,
             float* __restrict__ out)
{
    __shared__ double red[48];
    const double ref = (double)ws_f[6];
    double ninc = 0.0, fsum = 0.0, lsum = 0.0;
    for (int w = threadIdx.x; w < NWIN; w += blockDim.x) {
        double c   = (double)g_seg[w];
        double sp  = (double)g_seg[NWIN + w];
        double ar  = (double)g_seg[2 * NWIN + w];
        double spd = (double)g_seg[3 * NWIN + w];
        double inc = (c >= 2.0 && sp >= 1e-6) ? 1.0 : 0.0;
        double dmean = spd / (sp + 1e-6);
        double rr = ar / (1000.0 + 1e-6);
        double bu = fmax(rr - 1.0, 0.0);
        double flow = bu * bu;
        double rho = fmin(fmax(rr, 0.0), 0.99);
        double dth = 1.0 / (1.0 - rho + 1e-6);
        double lat = fmax(dth - dmean / ref, 0.0);
        ninc += inc; fsum += flow * inc; lsum += lat * inc;
    }
    for (int off = 32; off > 0; off >>= 1) {
        ninc += __shfl_down(ninc, off);
        fsum += __shfl_down(fsum, off);
        lsum += __shfl_down(lsum, off);
    }
    int wid = threadIdx.x >> 6, lane = threadIdx.x & 63;
    if (lane == 0) { red[wid] = ninc; red[16 + wid] = fsum; red[32 + wid] = lsum; }
    __syncthreads();
    if (threadIdx.x == 0) {
        double n_i = 0.0, f_s = 0.0, l_s = 0.0;
        int nw = (int)blockDim.x >> 6;
        for (int w = 0; w < nw; ++w) { n_i += red[w]; f_s += red[16 + w]; l_s += red[32 + w]; }
        double safe = fmax(n_i, 1.0);
        double l_flow = (n_i > 0.0) ? f_s / safe : 0.0;
        double l_lat  = (n_i > 0.0) ? l_s / safe : 0.0;
        double den = (double)ws_u64[1];
        double l_data = (den > 0.0) ? (double)ws_u64[0] / den : 0.0;   // scales cancel
        bool any = ws_u[5] > 0u;
        if (!any) { l_data = 0.0; l_flow = 0.0; l_lat = 0.0; }
        out[0] = (float)(l_data + 0.1 * l_flow + 0.1 * l_lat);
        out[1] = (float)l_data;
        out[2] = (float)l_flow;
        out[3] = (float)l_lat;
    }
}

extern "C" void kernel_launch(void* const* d_in, const int* in_sizes, int n_in,
                              void* d_out, int out_size, void* d_ws, size_t ws_size,
                              hipStream_t stream)
{
    const float2* logits = (const float2*)d_in[0];
    const int* y = (const int*)d_in[1];
    const int* mask = (const int*)d_in[2];       // bool delivered as int32
    const float4* xraw = (const float4*)d_in[3];
    const int* widx = (const int*)d_in[4];
    const float* cw = (const float*)d_in[5];
    float* out = (float*)d_out;
    const int n = in_sizes[1];   // N from y

    unsigned char* ws8 = (unsigned char*)d_ws;
    unsigned long long* ws_u64 = (unsigned long long*)ws8;
    float* ws_f = (float*)ws8;
    unsigned* ws_u = (unsigned*)ws8;
    float* g_seg = (float*)(ws8 + OFF_SEG);
    unsigned* g_h1 = (unsigned*)(ws8 + OFF_H1);
    unsigned* g_h2 = (unsigned*)(ws8 + OFF_H2);
    unsigned* g_h3 = (unsigned*)(ws8 + OFF_H3);
    unsigned* g_seg_u32 = (unsigned*)(ws8 + OFF_SEGU);

    const size_t part_bytes = (size_t)GRID_MAIN * 4 * NWIN * 4;  // 32 MB
    const size_t keys_bytes = (size_t)n * 4u;
    unsigned* part = (unsigned*)(ws8 + OFF_PART);
    unsigned* keys = (unsigned*)(ws8 + OFF_PART);
    int use_part = 0, use_keys = 0;
    if (ws_size >= OFF_PART + part_bytes + keys_bytes) {
        use_part = 1; use_keys = 1;
        keys = (unsigned*)(ws8 + OFF_PART + part_bytes);
    } else if (ws_size >= OFF_PART + part_bytes) {
        use_part = 1;
    } else if (ws_size >= OFF_PART + keys_bytes) {
        use_keys = 1;
    }

    hipMemsetAsync(d_ws, 0, OFF_PART, stream);   // header + g_seg(+u32) + hists

    // diagnostics (rocprof-only; write into part region, overwritten by k_main)
    if (use_part) {
        k_abl_load<<<GRID_MAIN, BLOCK_MAIN, 0, stream>>>(logits, y, mask, xraw,
                                                         widx, part, n);
        k_abl_atom<<<GRID_MAIN, BLOCK_MAIN, 0, stream>>>(logits, y, mask, xraw,
                                                         widx, part, n);
    }

    k_main<<<GRID_MAIN, BLOCK_MAIN, 0, stream>>>(logits, y, mask, xraw, widx, cw,
                                                 ws_u64, ws_u, g_seg_u32, part, keys,
                                                 g_h1, use_part, use_keys, n);
    if (use_part)
        k_reduce<<<128, 128, 0, stream>>>(part, g_seg);
    else
        k_convert<<<64, 256, 0, stream>>>(g_seg_u32, g_seg);
    k_scan1<<<1, 256, 0, stream>>>(ws_u, ws_f, g_h1);
    k_hist2<<<512, 256, 0, stream>>>(keys, xraw, mask, widx, use_keys, n, ws_u, g_h2);
    k_scan2<<<1, 256, 0, stream>>>(ws_u, g_h2);
    k_hist3<<<512, 256, 0, stream>>>(keys, xraw, mask, widx, use_keys, n, ws_u, g_h3);
    k_scan3<<<1, 256, 0, stream>>>(ws_u, ws_f, g_h3);
    k_final<<<1, 1024, 0, stream>>>(g_seg, ws_u64, ws_f, ws_u, out);
}

// Round 6
// 273.753 us; speedup vs baseline: 1.5960x; 1.5960x over previous
//
#include <hip/hip_runtime.h>

#define NWIN 4096
#define EPSF 1e-6f
#define GRID_MAIN 512
#define BLOCK_MAIN 512

// fixed-point scales (u32 LDS atomics; native ds_add_u32, fire-and-forget)
#define SCALE_P   2097152.0f     // 2^21  sum_p
#define SCALE_R   131072.0f      // 2^17  agg_rate / sum_pd
#define INV_P     (1.0/2097152.0)
#define INV_R     (1.0/131072.0)
#define SCALE_CE  1048576.0f     // 2^20  CE num/den (scales cancel in the ratio)

// ---------------- workspace layout (bytes) ----------------
//  byte 0:  u64 ce_num        byte 8:  u64 ce_den
//  byte 16: u32 n_valid(u[4]) byte 20: u32 n_mask(u[5])
//  byte 24: f32 ref_dobs(f[6]) byte 28: f32 frac(f[7])
//  byte 32,36: u32 prefixes (u[8],u[9])  byte 40,44: u32 ranks (u[10],u[11])
#define OFF_SEG   256            // float g_seg[16384]
#define OFF_H1    65792          // u32[2048]
#define OFF_H2    73984          // u32[2*2048]
#define OFF_H3    90368          // u32[2*1024]
#define OFF_SEGU  131072         // u32 g_seg_u32[16384]
#define OFF_PART  262144         // GRID_MAIN x 64KB u32 partials; keys after

__device__ __forceinline__ unsigned make_key_raw(const float4* __restrict__ xraw,
                                                 const int* __restrict__ mask,
                                                 const int* __restrict__ widx, int i)
{
    int wi = widx[i];
    int m = mask[i];
    if (wi < 0 || !m) return 0x7F800000u;
    float d = fmaxf(xraw[i].z, 0.0f);
    unsigned k = __float_as_uint(d);
    return (k == 0x80000000u) ? 0u : k;
}

// ---------------- per-element fused work ----------------
__device__ __forceinline__ void process_elem(
    float lgx, float lgy, int yi, int mi, float xz, float xw, int wi,
    float cw0, float cw1, unsigned* keyOut,
    float& num, float& den, unsigned& nv, unsigned& nm, unsigned& zc,
    unsigned* s_seg, unsigned* s_h1)
{
    float wy = yi ? cw1 : cw0;
    float mx = fmaxf(lgx, lgy);
    float lse = mx + __logf(__expf(lgx - mx) + __expf(lgy - mx));
    float nll = lse - (yi ? lgy : lgx);
    if (mi) { nm++; num += wy * nll; den += wy; }

    bool vq = (wi >= 0) && mi;
    unsigned key = 0x7F800000u;
    if (vq) {
        nv++;
        float d = fmaxf(xz, 0.0f);
        key = __float_as_uint(d);
        if (key == 0x80000000u) key = 0u;
    }
    *keyOut = key;

    if (key == 0u) zc++;
    else atomicAdd(&s_h1[key >> 21], 1u);

    if (vq && wi < NWIN) {
        float p = 1.0f / (1.0f + __expf(lgx - lgy));
        float rate = fmaxf(xw, 0.0f);
        float dob  = fmaxf(xz, 0.0f);
        atomicAdd(&s_seg[wi], 1u);
        atomicAdd(&s_seg[NWIN + wi],     (unsigned)(p * SCALE_P + 0.5f));
        atomicAdd(&s_seg[2 * NWIN + wi], (unsigned)(p * rate * SCALE_R + 0.5f));
        atomicAdd(&s_seg[3 * NWIN + wi], (unsigned)(p * dob  * SCALE_R + 0.5f));
    }
}

// one quad's worth of input, kept whole in registers (static access only)
struct Quad {
    float4 lgA, lgB;
    int4 y4, m4, w4;
    float4 x0, x1, x2, x3;
};

__device__ __forceinline__ Quad load_quad(const float4* __restrict__ lg4,
                                          const int4* __restrict__ y4p,
                                          const int4* __restrict__ m4p,
                                          const int4* __restrict__ w4p,
                                          const float4* __restrict__ xraw, int q)
{
    Quad t;
    t.lgA = lg4[2 * q]; t.lgB = lg4[2 * q + 1];
    t.y4 = y4p[q]; t.m4 = m4p[q]; t.w4 = w4p[q];
    t.x0 = xraw[4 * q]; t.x1 = xraw[4 * q + 1];
    t.x2 = xraw[4 * q + 2]; t.x3 = xraw[4 * q + 3];
    return t;
}

// ---------------- main fused pass (reg-pipelined) ----------------
extern "C" __global__ __launch_bounds__(BLOCK_MAIN, 2)
void k_main(const float2* __restrict__ logits, const int* __restrict__ y,
            const int* __restrict__ mask, const float4* __restrict__ xraw,
            const int* __restrict__ widx, const float* __restrict__ cw,
            unsigned long long* __restrict__ ws_u64, unsigned* __restrict__ ws_u,
            unsigned* __restrict__ g_seg_u32, unsigned* __restrict__ part,
            unsigned* __restrict__ keys, unsigned* __restrict__ gh1,
            int use_part, int use_keys, int n)
{
    __shared__ unsigned s_seg[4 * NWIN];   // 64 KB: cnt | p<<21 | rate<<17 | pd<<17
    __shared__ unsigned s_h1[2048];        // 8 KB level-1 histogram
    for (int j = threadIdx.x; j < 4 * NWIN; j += BLOCK_MAIN) s_seg[j] = 0u;
    for (int j = threadIdx.x; j < 2048; j += BLOCK_MAIN) s_h1[j] = 0u;
    __syncthreads();

    const float cw0 = cw[0], cw1 = cw[1];
    float num = 0.0f, den = 0.0f;
    unsigned nv = 0u, nm = 0u, zc = 0u;

    const int nth = GRID_MAIN * BLOCK_MAIN;
    const int gtid = blockIdx.x * BLOCK_MAIN + threadIdx.x;
    const int nq = n >> 2;

    const float4* lg4 = (const float4*)logits;
    const int4* y4p = (const int4*)y;
    const int4* m4p = (const int4*)mask;
    const int4* w4p = (const int4*)widx;

#define PROCESS_QUAD(T, Q)                                                        \
    do {                                                                          \
        uint4 kq;                                                                 \
        process_elem(T.lgA.x, T.lgA.y, T.y4.x, T.m4.x, T.x0.z, T.x0.w, T.w4.x,    \
                     cw0, cw1, &kq.x, num, den, nv, nm, zc, s_seg, s_h1);         \
        process_elem(T.lgA.z, T.lgA.w, T.y4.y, T.m4.y, T.x1.z, T.x1.w, T.w4.y,    \
                     cw0, cw1, &kq.y, num, den, nv, nm, zc, s_seg, s_h1);         \
        process_elem(T.lgB.x, T.lgB.y, T.y4.z, T.m4.z, T.x2.z, T.x2.w, T.w4.z,    \
                     cw0, cw1, &kq.z, num, den, nv, nm, zc, s_seg, s_h1);         \
        process_elem(T.lgB.z, T.lgB.w, T.y4.w, T.m4.w, T.x3.z, T.x3.w, T.w4.w,    \
                     cw0, cw1, &kq.w, num, den, nv, nm, zc, s_seg, s_h1);         \
        if (use_keys) ((uint4*)keys)[Q] = kq;                                     \
    } while (0)

    int q = gtid;
    if (q < nq) {
        Quad cur = load_quad(lg4, y4p, m4p, w4p, xraw, q);
        int qn = q + nth;
        while (qn < nq) {
            Quad nxt = load_quad(lg4, y4p, m4p, w4p, xraw, qn);  // prefetch
            PROCESS_QUAD(cur, q);          // compute overlaps nxt's latency
            cur = nxt; q = qn; qn += nth;
        }
        PROCESS_QUAD(cur, q);
    }
    for (int i = (nq << 2) + gtid; i < n; i += nth) {   // tail (n%4)
        float2 lg = logits[i];
        float4 xr = xraw[i];
        unsigned k;
        process_elem(lg.x, lg.y, y[i], mask[i], xr.z, xr.w, widx[i],
                     cw0, cw1, &k, num, den, nv, nm, zc, s_seg, s_h1);
        if (use_keys) keys[i] = k;
    }
#undef PROCESS_QUAD

    for (int off = 32; off > 0; off >>= 1) {
        num += __shfl_down(num, off);
        den += __shfl_down(den, off);
        nv  += __shfl_down(nv, off);
        nm  += __shfl_down(nm, off);
        zc  += __shfl_down(zc, off);
    }
    if ((threadIdx.x & 63) == 0) {
        atomicAdd(&ws_u64[0], (unsigned long long)(num * SCALE_CE + 0.5f));
        atomicAdd(&ws_u64[1], (unsigned long long)(den * SCALE_CE + 0.5f));
        atomicAdd(&ws_u[4], nv);
        atomicAdd(&ws_u[5], nm);
        if (zc) atomicAdd(&s_h1[0], zc);
    }
    __syncthreads();

    if (use_part) {
        uint4* dst = (uint4*)(part + (size_t)blockIdx.x * (4 * NWIN));
        const uint4* src = (const uint4*)s_seg;
        for (int j = threadIdx.x; j < NWIN; j += BLOCK_MAIN) dst[j] = src[j];
    } else {
        for (int j = threadIdx.x; j < 4 * NWIN; j += BLOCK_MAIN) {
            unsigned v = s_seg[j];
            if (v) atomicAdd(&g_seg_u32[j], v);
        }
    }
    for (int j = threadIdx.x; j < 2048; j += BLOCK_MAIN) {
        unsigned v = s_h1[j];
        if (v) atomicAdd(&gh1[j], v);
    }
}

// ---------------- partial reduction: 512 u32 partials -> g_seg_u32 ----------------
// grid 256: (bin-group 0..63) x (partial-chunk 0..3); 4 waves/CU, 8-deep MLP
extern "C" __global__ __launch_bounds__(256)
void k_reduce(const unsigned* __restrict__ part, unsigned* __restrict__ g_seg_u32)
{
    const int bin = (blockIdx.x & 63) * 256 + threadIdx.x;
    const int c = blockIdx.x >> 6;
    const unsigned* p = part + (size_t)c * (GRID_MAIN / 4) * (4 * NWIN) + bin;
    unsigned s = 0u;
#pragma unroll 8
    for (int b = 0; b < GRID_MAIN / 4; ++b) s += p[(size_t)b * (4 * NWIN)];
    if (s) atomicAdd(&g_seg_u32[bin], s);
}

// convert u32 fixed-point sums to float g_seg
extern "C" __global__ __launch_bounds__(256)
void k_convert(const unsigned* __restrict__ gsu, float* __restrict__ g_seg)
{
    const int j = blockIdx.x * 256 + threadIdx.x;   // grid 64
    double inv = (j < NWIN) ? 1.0 : (j < 2 * NWIN) ? INV_P : INV_R;
    g_seg[j] = (float)((double)gsu[j] * inv);
}

// ---------------- histogram passes 2 and 3 (4-deep load batching) ----------------
__device__ __forceinline__ void h2_one(unsigned key, unsigned p0, unsigned p1,
                                       unsigned* h)
{
    unsigned top = key >> 21;
    unsigned sub = (key >> 10) & 2047u;
    if (top == p0) atomicAdd(&h[sub], 1u);
    if (top == p1) atomicAdd(&h[2048 + sub], 1u);
}

extern "C" __global__ __launch_bounds__(256)
void k_hist2(const unsigned* __restrict__ keys, const float4* __restrict__ xraw,
             const int* __restrict__ mask, const int* __restrict__ widx,
             int use_keys, int n, const unsigned* __restrict__ ws_u,
             unsigned* __restrict__ gh)
{
    __shared__ unsigned h[2 * 2048];
    for (int j = threadIdx.x; j < 2 * 2048; j += 256) h[j] = 0u;
    __syncthreads();
    const unsigned p0 = ws_u[8], p1 = ws_u[9];
    const int nthr = gridDim.x * blockDim.x;
    const int gtid = blockIdx.x * blockDim.x + threadIdx.x;
    const int nq = n >> 2;
    if (use_keys) {
        const uint4* k4 = (const uint4*)keys;
        int base = gtid;
        for (; base + 3 * nthr < nq; base += 4 * nthr) {
            uint4 a = k4[base], b = k4[base + nthr];
            uint4 c = k4[base + 2 * nthr], d = k4[base + 3 * nthr];
            h2_one(a.x, p0, p1, h); h2_one(a.y, p0, p1, h);
            h2_one(a.z, p0, p1, h); h2_one(a.w, p0, p1, h);
            h2_one(b.x, p0, p1, h); h2_one(b.y, p0, p1, h);
            h2_one(b.z, p0, p1, h); h2_one(b.w, p0, p1, h);
            h2_one(c.x, p0, p1, h); h2_one(c.y, p0, p1, h);
            h2_one(c.z, p0, p1, h); h2_one(c.w, p0, p1, h);
            h2_one(d.x, p0, p1, h); h2_one(d.y, p0, p1, h);
            h2_one(d.z, p0, p1, h); h2_one(d.w, p0, p1, h);
        }
        for (; base < nq; base += nthr) {
            uint4 a = k4[base];
            h2_one(a.x, p0, p1, h); h2_one(a.y, p0, p1, h);
            h2_one(a.z, p0, p1, h); h2_one(a.w, p0, p1, h);
        }
        for (int i = (nq << 2) + gtid; i < n; i += nthr)
            h2_one(keys[i], p0, p1, h);
    } else {
        for (int i = gtid; i < n; i += nthr)
            h2_one(make_key_raw(xraw, mask, widx, i), p0, p1, h);
    }
    __syncthreads();
    for (int j = threadIdx.x; j < 2 * 2048; j += 256)
        if (h[j]) atomicAdd(&gh[j], h[j]);
}

__device__ __forceinline__ void h3_one(unsigned key, unsigned p0, unsigned p1,
                                       unsigned* h)
{
    unsigned top = key >> 10;
    unsigned sub = key & 1023u;
    if (top == p0) atomicAdd(&h[sub], 1u);
    if (top == p1) atomicAdd(&h[1024 + sub], 1u);
}

extern "C" __global__ __launch_bounds__(256)
void k_hist3(const unsigned* __restrict__ keys, const float4* __restrict__ xraw,
             const int* __restrict__ mask, const int* __restrict__ widx,
             int use_keys, int n, const unsigned* __restrict__ ws_u,
             unsigned* __restrict__ gh)
{
    __shared__ unsigned h[2 * 1024];
    for (int j = threadIdx.x; j < 2 * 1024; j += 256) h[j] = 0u;
    __syncthreads();
    const unsigned p0 = ws_u[8], p1 = ws_u[9];
    const int nthr = gridDim.x * blockDim.x;
    const int gtid = blockIdx.x * blockDim.x + threadIdx.x;
    const int nq = n >> 2;
    if (use_keys) {
        const uint4* k4 = (const uint4*)keys;
        int base = gtid;
        for (; base + 3 * nthr < nq; base += 4 * nthr) {
            uint4 a = k4[base], b = k4[base + nthr];
            uint4 c = k4[base + 2 * nthr], d = k4[base + 3 * nthr];
            h3_one(a.x, p0, p1, h); h3_one(a.y, p0, p1, h);
            h3_one(a.z, p0, p1, h); h3_one(a.w, p0, p1, h);
            h3_one(b.x, p0, p1, h); h3_one(b.y, p0, p1, h);
            h3_one(b.z, p0, p1, h); h3_one(b.w, p0, p1, h);
            h3_one(c.x, p0, p1, h); h3_one(c.y, p0, p1, h);
            h3_one(c.z, p0, p1, h); h3_one(c.w, p0, p1, h);
            h3_one(d.x, p0, p1, h); h3_one(d.y, p0, p1, h);
            h3_one(d.z, p0, p1, h); h3_one(d.w, p0, p1, h);
        }
        for (; base < nq; base += nthr) {
            uint4 a = k4[base];
            h3_one(a.x, p0, p1, h); h3_one(a.y, p0, p1, h);
            h3_one(a.z, p0, p1, h); h3_one(a.w, p0, p1, h);
        }
        for (int i = (nq << 2) + gtid; i < n; i += nthr)
            h3_one(keys[i], p0, p1, h);
    } else {
        for (int i = gtid; i < n; i += nthr)
            h3_one(make_key_raw(xraw, mask, widx, i), p0, p1, h);
    }
    __syncthreads();
    for (int j = threadIdx.x; j < 2 * 1024; j += 256)
        if (h[j]) atomicAdd(&gh[j], h[j]);
}

// ---------------- single-block scan + rank search ----------------
__device__ void scan_search(const unsigned* __restrict__ gh, int NB, unsigned rank,
                            unsigned* sv, unsigned* wsb, unsigned* ret)
{
    const int tid = threadIdx.x;
    for (int j = tid; j < NB; j += 256) sv[j] = gh[j];
    __syncthreads();
    const int E = NB >> 8;
    const int base = tid * E;
    unsigned loc = 0u;
    for (int e = 0; e < E; ++e) loc += sv[base + e];
    unsigned inc = loc;
    const int lane = tid & 63;
    for (int off = 1; off < 64; off <<= 1) {
        unsigned u = __shfl_up(inc, off);
        if (lane >= off) inc += u;
    }
    const int wid = tid >> 6;
    if (lane == 63) wsb[wid] = inc;
    __syncthreads();
    if (tid == 0) {
        unsigned run = 0u;
        for (int w = 0; w < 4; ++w) { unsigned t = wsb[w]; wsb[w] = run; run += t; }
    }
    __syncthreads();
    unsigned c = wsb[wid] + (inc - loc);
    for (int e = 0; e < E; ++e) {
        unsigned hv = sv[base + e];
        if (rank >= c && rank < c + hv) { ret[0] = (unsigned)(base + e); ret[1] = rank - c; }
        c += hv;
    }
    __syncthreads();
}

extern "C" __global__ __launch_bounds__(256)
void k_scan1(unsigned* __restrict__ ws_u, float* __restrict__ ws_f,
             const unsigned* __restrict__ gh)
{
    __shared__ unsigned sv[2048];
    __shared__ unsigned wsb[4];
    __shared__ unsigned ret[2];
    __shared__ unsigned rk[2];
    if (threadIdx.x == 0) {
        int n = (int)ws_u[4];
        float nf = (float)(n - 1);
        float pos = fmaxf(0.75f * nf, 0.0f);
        float lo = floorf(pos);
        ws_f[7] = pos - lo;
        rk[0] = (unsigned)lo;
        rk[1] = (unsigned)ceilf(pos);
    }
    __syncthreads();
    unsigned r0 = rk[0], r1 = rk[1];
    scan_search(gh, 2048, r0, sv, wsb, ret);
    if (threadIdx.x == 0) { ws_u[8] = ret[0]; ws_u[10] = ret[1]; }
    scan_search(gh, 2048, r1, sv, wsb, ret);
    if (threadIdx.x == 0) { ws_u[9] = ret[0]; ws_u[11] = ret[1]; }
}

extern "C" __global__ __launch_bounds__(256)
void k_scan2(unsigned* __restrict__ ws_u, const unsigned* __restrict__ gh)
{
    __shared__ unsigned sv[2048];
    __shared__ unsigned wsb[4];
    __shared__ unsigned ret[2];
    unsigned p0 = ws_u[8], p1 = ws_u[9];
    unsigned r0 = ws_u[10], r1 = ws_u[11];
    scan_search(gh, 2048, r0, sv, wsb, ret);
    if (threadIdx.x == 0) { ws_u[8] = (p0 << 11) | ret[0]; ws_u[10] = ret[1]; }
    scan_search(gh + 2048, 2048, r1, sv, wsb, ret);
    if (threadIdx.x == 0) { ws_u[9] = (p1 << 11) | ret[0]; ws_u[11] = ret[1]; }
}

extern "C" __global__ __launch_bounds__(256)
void k_scan3(unsigned* __restrict__ ws_u, float* __restrict__ ws_f,
             const unsigned* __restrict__ gh)
{
    __shared__ unsigned sv[2048];
    __shared__ unsigned wsb[4];
    __shared__ unsigned ret[2];
    unsigned p0 = ws_u[8], p1 = ws_u[9];
    unsigned r0 = ws_u[10], r1 = ws_u[11];
    scan_search(gh, 1024, r0, sv, wsb, ret);
    float v0 = __uint_as_float((p0 << 10) | ret[0]);
    scan_search(gh + 1024, 1024, r1, sv, wsb, ret);
    float v1 = __uint_as_float((p1 << 10) | ret[0]);
    if (threadIdx.x == 0) {
        int n = (int)ws_u[4];
        float frac = ws_f[7];
        float q = v0 * (1.0f - frac) + v1 * frac;
        ws_f[6] = (n > 0) ? fmaxf(q, EPSF) : 1.0f;
    }
}

// ---------------- finalize ----------------
extern "C" __global__ __launch_bounds__(1024)
void k_final(const float* __restrict__ g_seg, const unsigned long long* __restrict__ ws_u64,
             const float* __restrict__ ws_f, const unsigned* __restrict__ ws_u,
             float* __restrict__ out)
{
    __shared__ double red[48];
    const double ref = (double)ws_f[6];
    double ninc = 0.0, fsum = 0.0, lsum = 0.0;
    for (int w = threadIdx.x; w < NWIN; w += blockDim.x) {
        double c   = (double)g_seg[w];
        double sp  = (double)g_seg[NWIN + w];
        double ar  = (double)g_seg[2 * NWIN + w];
        double spd = (double)g_seg[3 * NWIN + w];
        double inc = (c >= 2.0 && sp >= 1e-6) ? 1.0 : 0.0;
        double dmean = spd / (sp + 1e-6);
        double rr = ar / (1000.0 + 1e-6);
        double bu = fmax(rr - 1.0, 0.0);
        double flow = bu * bu;
        double rho = fmin(fmax(rr, 0.0), 0.99);
        double dth = 1.0 / (1.0 - rho + 1e-6);
        double lat = fmax(dth - dmean / ref, 0.0);
        ninc += inc; fsum += flow * inc; lsum += lat * inc;
    }
    for (int off = 32; off > 0; off >>= 1) {
        ninc += __shfl_down(ninc, off);
        fsum += __shfl_down(fsum, off);
        lsum += __shfl_down(lsum, off);
    }
    int wid = threadIdx.x >> 6, lane = threadIdx.x & 63;
    if (lane == 0) { red[wid] = ninc; red[16 + wid] = fsum; red[32 + wid] = lsum; }
    __syncthreads();
    if (threadIdx.x == 0) {
        double n_i = 0.0, f_s = 0.0, l_s = 0.0;
        int nw = (int)blockDim.x >> 6;
        for (int w = 0; w < nw; ++w) { n_i += red[w]; f_s += red[16 + w]; l_s += red[32 + w]; }
        double safe = fmax(n_i, 1.0);
        double l_flow = (n_i > 0.0) ? f_s / safe : 0.0;
        double l_lat  = (n_i > 0.0) ? l_s / safe : 0.0;
        double den = (double)ws_u64[1];
        double l_data = (den > 0.0) ? (double)ws_u64[0] / den : 0.0;
        bool any = ws_u[5] > 0u;
        if (!any) { l_data = 0.0; l_flow = 0.0; l_lat = 0.0; }
        out[0] = (float)(l_data + 0.1 * l_flow + 0.1 * l_lat);
        out[1] = (float)l_data;
        out[2] = (float)l_flow;
        out[3] = (float)l_lat;
    }
}

extern "C" void kernel_launch(void* const* d_in, const int* in_sizes, int n_in,
                              void* d_out, int out_size, void* d_ws, size_t ws_size,
                              hipStream_t stream)
{
    const float2* logits = (const float2*)d_in[0];
    const int* y = (const int*)d_in[1];
    const int* mask = (const int*)d_in[2];       // bool delivered as int32
    const float4* xraw = (const float4*)d_in[3];
    const int* widx = (const int*)d_in[4];
    const float* cw = (const float*)d_in[5];
    float* out = (float*)d_out;
    const int n = in_sizes[1];   // N from y

    unsigned char* ws8 = (unsigned char*)d_ws;
    unsigned long long* ws_u64 = (unsigned long long*)ws8;
    float* ws_f = (float*)ws8;
    unsigned* ws_u = (unsigned*)ws8;
    float* g_seg = (float*)(ws8 + OFF_SEG);
    unsigned* g_h1 = (unsigned*)(ws8 + OFF_H1);
    unsigned* g_h2 = (unsigned*)(ws8 + OFF_H2);
    unsigned* g_h3 = (unsigned*)(ws8 + OFF_H3);
    unsigned* g_seg_u32 = (unsigned*)(ws8 + OFF_SEGU);

    const size_t part_bytes = (size_t)GRID_MAIN * 4 * NWIN * 4;  // 32 MB
    const size_t keys_bytes = (size_t)n * 4u;
    unsigned* part = (unsigned*)(ws8 + OFF_PART);
    unsigned* keys = (unsigned*)(ws8 + OFF_PART);
    int use_part = 0, use_keys = 0;
    if (ws_size >= OFF_PART + part_bytes + keys_bytes) {
        use_part = 1; use_keys = 1;
        keys = (unsigned*)(ws8 + OFF_PART + part_bytes);
    } else if (ws_size >= OFF_PART + part_bytes) {
        use_part = 1;
    } else if (ws_size >= OFF_PART + keys_bytes) {
        use_keys = 1;
    }

    hipMemsetAsync(d_ws, 0, OFF_PART, stream);   // header + g_seg(+u32) + hists

    k_main<<<GRID_MAIN, BLOCK_MAIN, 0, stream>>>(logits, y, mask, xraw, widx, cw,
                                                 ws_u64, ws_u, g_seg_u32, part, keys,
                                                 g_h1, use_part, use_keys, n);
    if (use_part)
        k_reduce<<<256, 256, 0, stream>>>(part, g_seg_u32);
    k_convert<<<64, 256, 0, stream>>>(g_seg_u32, g_seg);
    k_scan1<<<1, 256, 0, stream>>>(ws_u, ws_f, g_h1);
    k_hist2<<<1024, 256, 0, stream>>>(keys, xraw, mask, widx, use_keys, n, ws_u, g_h2);
    k_scan2<<<1, 256, 0, stream>>>(ws_u, g_h2);
    k_hist3<<<1024, 256, 0, stream>>>(keys, xraw, mask, widx, use_keys, n, ws_u, g_h3);
    k_scan3<<<1, 256, 0, stream>>>(ws_u, ws_f, g_h3);
    k_final<<<1, 1024, 0, stream>>>(g_seg, ws_u64, ws_f, ws_u, out);
}